// Round 1
// baseline (140.254 us; speedup 1.0000x reference)
//
#include <hip/hip_runtime.h>

// MultiHeadSelfAttentionConv: B=4, C=512, L=2048, H=8, Ch=64
// Pipeline: proj (bf16 MFMA GEMM) -> ws {Qt,Kt bf16 (b,h,l,c); V bf16 natural}
//           attn (flash, bf16 MFMA, fp32 softmax) -> d_out fp32 (b,h,l,c) flat

typedef unsigned short u16;
typedef unsigned int   u32;
typedef short bf16x8 __attribute__((ext_vector_type(8)));
typedef float f32x4  __attribute__((ext_vector_type(4)));

__device__ __forceinline__ u16 f2b(float f) {
    u32 u = __float_as_uint(f);
    u += 0x7FFFu + ((u >> 16) & 1u);   // round-to-nearest-even
    return (u16)(u >> 16);
}

// ---------------- Projection kernel ----------------
// grid (32 ltiles, 24 otiles, 4 b), 256 thr. o-tile 64 rows of stacked [q;k;v].
__global__ __launch_bounds__(256) void proj_kernel(
    const float* __restrict__ x,
    const float* __restrict__ wq, const float* __restrict__ bq,
    const float* __restrict__ wk, const float* __restrict__ bk,
    const float* __restrict__ wv, const float* __restrict__ bv,
    u16* __restrict__ qt, u16* __restrict__ kt, u16* __restrict__ vv)
{
    const int lt = blockIdx.x, ot = blockIdx.y, b = blockIdx.z;
    const int l0 = lt * 64;
    const int o0 = ot * 64;
    const int sel = o0 >> 9;        // 0=q 1=k 2=v
    const int ol0 = o0 & 511;

    const float* __restrict__ w    = (sel == 0) ? wq : (sel == 1) ? wk : wv;
    const float* __restrict__ bias = (sel == 0) ? bq : (sel == 1) ? bk : bv;

    __shared__ u16 wt[64 * 72];     // W tile (o,c), bf16
    __shared__ u16 xt[64 * 72];     // X tile transposed (l,c), XOR-swizzled

    const int tid = threadIdx.x;
    const int wid = tid >> 6;
    const int lane = tid & 63;
    const int j = lane & 15;        // MFMA i/j index
    const int g = lane >> 4;        // MFMA k-group

    f32x4 acc[4];
#pragma unroll
    for (int i = 0; i < 4; ++i) acc[i] = (f32x4){0.f, 0.f, 0.f, 0.f};

    for (int c0 = 0; c0 < 512; c0 += 64) {
        // stage W (64 o x 64 c)
#pragma unroll
        for (int it = 0; it < 4; ++it) {
            int s = tid + it * 256;              // 0..1023
            int row = s >> 4, c4 = (s & 15) * 4;
            const float4 w4 = *(const float4*)(w + (size_t)(ol0 + row) * 512 + c0 + c4);
            u16* d = wt + row * 72 + c4;
            d[0] = f2b(w4.x); d[1] = f2b(w4.y); d[2] = f2b(w4.z); d[3] = f2b(w4.w);
        }
        // stage X transposed: xt[l][c ^ swz(l)]
#pragma unroll
        for (int it = 0; it < 4; ++it) {
            int s = tid + it * 256;
            int crow = s >> 4, l4 = (s & 15) * 4;
            const float4 x4 = *(const float4*)(x + ((size_t)b * 512 + c0 + crow) * 2048 + l0 + l4);
            float vals[4] = {x4.x, x4.y, x4.z, x4.w};
#pragma unroll
            for (int jj = 0; jj < 4; ++jj) {
                int l = l4 + jj;
                xt[l * 72 + (crow ^ (((l >> 2) & 7) << 3))] = f2b(vals[jj]);
            }
        }
        __syncthreads();
#pragma unroll
        for (int kk = 0; kk < 64; kk += 32) {
            bf16x8 af = *(const bf16x8*)(wt + (wid * 16 + j) * 72 + kk + g * 8);
#pragma unroll
            for (int ls = 0; ls < 4; ++ls) {
                int l = ls * 16 + j;
                bf16x8 bfr = *(const bf16x8*)(xt + l * 72 + ((kk + g * 8) ^ (((l >> 2) & 7) << 3)));
                acc[ls] = __builtin_amdgcn_mfma_f32_16x16x32_bf16(af, bfr, acc[ls], 0, 0, 0);
            }
        }
        __syncthreads();
    }

    const int o_off = wid * 16 + g * 4;          // channel offset within 64-tile (one head)
    float bb[4];
#pragma unroll
    for (int r = 0; r < 4; ++r) bb[r] = bias[ol0 + o_off + r];

    if (sel < 2) {
        u16* __restrict__ dstbuf = (sel == 0) ? qt : kt;
        const float sc = (sel == 0) ? 0.125f : 1.0f;   // fold 1/sqrt(Ch) into q
        const int h = ol0 >> 6;
#pragma unroll
        for (int ls = 0; ls < 4; ++ls) {
            int l = l0 + ls * 16 + j;
            u16* d = dstbuf + (((size_t)(b * 8 + h)) * 2048 + l) * 64 + o_off;
            ushort4 pk;
            pk.x = f2b((acc[ls][0] + bb[0]) * sc);
            pk.y = f2b((acc[ls][1] + bb[1]) * sc);
            pk.z = f2b((acc[ls][2] + bb[2]) * sc);
            pk.w = f2b((acc[ls][3] + bb[3]) * sc);
            *(ushort4*)d = pk;
        }
    } else {
#pragma unroll
        for (int ls = 0; ls < 4; ++ls) {
            int l = l0 + ls * 16 + j;
#pragma unroll
            for (int r = 0; r < 4; ++r) {
                vv[((size_t)b * 512 + ol0 + o_off + r) * 2048 + l] = f2b(acc[ls][r] + bb[r]);
            }
        }
    }
}

// ---------------- Flash attention kernel ----------------
// grid (32 ltiles, 32 bh), 256 thr. Wave w owns q-rows [l0+16w, l0+16w+16).
// Computes St = K·Q^T (m rows, l cols) so softmax stats are lane-group local.
__global__ __launch_bounds__(256) void attn_kernel(
    const u16* __restrict__ qt, const u16* __restrict__ kt,
    const u16* __restrict__ vv, float* __restrict__ out)
{
    const int bh = blockIdx.y;
    const int l0 = blockIdx.x * 64;
    const int tid = threadIdx.x;
    const int wid = tid >> 6;
    const int lane = tid & 63;
    const int j = lane & 15;
    const int g = lane >> 4;

    __shared__ u16 ktile[64 * 72];     // K tile (m,c)
    __shared__ u16 vt[64 * 72];        // V^T tile (c,m), XOR-swizzled
    __shared__ u16 pt[4 * 16 * 72];    // per-wave P^T staging (l,m)

    const u16* __restrict__ qbase = qt + ((size_t)bh * 2048 + l0 + wid * 16) * 64;
    bf16x8 qf0 = *(const bf16x8*)(qbase + j * 64 + g * 8);        // B[k=c][j=l], c 0..31
    bf16x8 qf1 = *(const bf16x8*)(qbase + j * 64 + 32 + g * 8);   // c 32..63

    const u16* __restrict__ kbase = kt + (size_t)bh * 2048 * 64;
    const u16* __restrict__ vbase = vv + (size_t)bh * 2048 * 64;  // v2 rows (m,c) flat

    float m_run = -1e30f, l_run = 0.f;
    f32x4 oacc[4];
#pragma unroll
    for (int i = 0; i < 4; ++i) oacc[i] = (f32x4){0.f, 0.f, 0.f, 0.f};

    for (int m0 = 0; m0 < 2048; m0 += 64) {
        // ---- stage K tile + transposed V tile ----
#pragma unroll
        for (int it = 0; it < 2; ++it) {
            int s = tid + it * 256;              // 0..511
            int row = s >> 3, c8 = (s & 7) * 8;
            *(bf16x8*)(ktile + row * 72 + c8) =
                *(const bf16x8*)(kbase + (size_t)(m0 + row) * 64 + c8);
            bf16x8 v8 = *(const bf16x8*)(vbase + (size_t)m0 * 64 + s * 8);
            int a = s & 7;                       // = c8/8
#pragma unroll
            for (int jj = 0; jj < 8; ++jj) {
                vt[(c8 + jj) * 72 + (row ^ ((a & 7) << 3))] = (u16)v8[jj];
            }
        }
        __syncthreads();

        // ---- St = K·Q^T : 4 m-subtiles of 16x16, K=64 ----
        f32x4 st[4];
#pragma unroll
        for (int mi = 0; mi < 4; ++mi) {
            bf16x8 a0 = *(const bf16x8*)(ktile + (mi * 16 + j) * 72 + g * 8);
            bf16x8 a1 = *(const bf16x8*)(ktile + (mi * 16 + j) * 72 + 32 + g * 8);
            f32x4 z = (f32x4){0.f, 0.f, 0.f, 0.f};
            z = __builtin_amdgcn_mfma_f32_16x16x32_bf16(a0, qf0, z, 0, 0, 0);
            z = __builtin_amdgcn_mfma_f32_16x16x32_bf16(a1, qf1, z, 0, 0, 0);
            st[mi] = z;
        }

        // ---- online softmax over this 64-m chunk (per l = lane&15) ----
        float pmax = st[0][0];
#pragma unroll
        for (int mi = 0; mi < 4; ++mi)
#pragma unroll
            for (int r = 0; r < 4; ++r) pmax = fmaxf(pmax, st[mi][r]);
        pmax = fmaxf(pmax, __shfl_xor(pmax, 16));
        pmax = fmaxf(pmax, __shfl_xor(pmax, 32));
        float m_new = fmaxf(m_run, pmax);
        float corr = __expf(m_run - m_new);
        float p[4][4];
        float psum = 0.f;
#pragma unroll
        for (int mi = 0; mi < 4; ++mi)
#pragma unroll
            for (int r = 0; r < 4; ++r) {
                p[mi][r] = __expf(st[mi][r] - m_new);
                psum += p[mi][r];
            }
        psum += __shfl_xor(psum, 16);
        psum += __shfl_xor(psum, 32);
        l_run = l_run * corr + psum;
        m_run = m_new;
#pragma unroll
        for (int ci = 0; ci < 4; ++ci) oacc[ci] = oacc[ci] * corr;

        // ---- write P^T to per-wave LDS (l row-major) ----
        u16* ptw = pt + wid * 16 * 72 + j * 72;
#pragma unroll
        for (int mi = 0; mi < 4; ++mi) {
            ushort4 pk;
            pk.x = f2b(p[mi][0]); pk.y = f2b(p[mi][1]);
            pk.z = f2b(p[mi][2]); pk.w = f2b(p[mi][3]);
            *(ushort4*)(ptw + mi * 16 + g * 4) = pk;
        }

        // ---- O^T += V^T · P^T : 4 c-subtiles, K=64 ----
#pragma unroll
        for (int ci = 0; ci < 4; ++ci) {
            int c = ci * 16 + j;
            int msk = ((c >> 3) & 7) << 3;
#pragma unroll
            for (int kk = 0; kk < 64; kk += 32) {
                bf16x8 av = *(const bf16x8*)(vt + c * 72 + ((kk + g * 8) ^ msk));
                bf16x8 bp = *(const bf16x8*)(pt + wid * 16 * 72 + j * 72 + kk + g * 8);
                oacc[ci] = __builtin_amdgcn_mfma_f32_16x16x32_bf16(av, bp, oacc[ci], 0, 0, 0);
            }
        }
        __syncthreads();
    }

    // ---- normalize + store (coalesced float4) ----
    float inv = 1.0f / l_run;
#pragma unroll
    for (int ci = 0; ci < 4; ++ci) {
        float4 o;
        o.x = oacc[ci][0] * inv;
        o.y = oacc[ci][1] * inv;
        o.z = oacc[ci][2] * inv;
        o.w = oacc[ci][3] * inv;
        float* d = out + ((size_t)bh * 2048 + l0 + wid * 16 + j) * 64 + ci * 16 + g * 4;
        *(float4*)d = o;
    }
}

extern "C" void kernel_launch(void* const* d_in, const int* in_sizes, int n_in,
                              void* d_out, int out_size, void* d_ws, size_t ws_size,
                              hipStream_t stream) {
    const float* x  = (const float*)d_in[0];
    const float* wq = (const float*)d_in[1];
    const float* bq = (const float*)d_in[2];
    const float* wk = (const float*)d_in[3];
    const float* bk = (const float*)d_in[4];
    const float* wv = (const float*)d_in[5];
    const float* bv = (const float*)d_in[6];
    float* out = (float*)d_out;

    u16* qt = (u16*)d_ws;                  // 4M bf16 = 8 MB
    u16* kt = qt + 4 * 1024 * 1024;        // 8 MB
    u16* vv = kt + 4 * 1024 * 1024;        // 8 MB

    proj_kernel<<<dim3(32, 24, 4), 256, 0, stream>>>(x, wq, bq, wk, bk, wv, bv, qt, kt, vv);
    attn_kernel<<<dim3(32, 32, 1), 256, 0, stream>>>(qt, kt, vv, out);
}

// Round 3
// 111.778 us; speedup vs baseline: 1.2548x; 1.2548x over previous
//
#include <hip/hip_runtime.h>

// B=4, C=512, L=2048, H=8, Ch=64, BH=32
// prep: w->bf16 wcat[1536][512]; x->xT[b][l][c] bf16
// proj: MFMA 32x32x16 -> qt,kt (b,h,l,c) bf16 (q scaled 0.125*log2e); vv natural
// vtrans: vv -> vtg (b,h,c,m) bf16  (V^T of the .view-reshaped v2)
// attn: flash, 32x32x16, dbuf global_load_lds staging, in-reg P via cvt_pk+permlane

typedef unsigned short u16;
typedef unsigned int   u32;
typedef short bf16x8 __attribute__((ext_vector_type(8)));
typedef u16  u16x8  __attribute__((ext_vector_type(8)));
typedef float f32x16 __attribute__((ext_vector_type(16)));

#define SCALE_Q 0.18033688011112042f  // 0.125 * log2(e)

__device__ __forceinline__ u16 f2b(float f) {
    u32 u = __float_as_uint(f);
    u += 0x7FFFu + ((u >> 16) & 1u);
    return (u16)(u >> 16);
}

__device__ __forceinline__ float exp2_(float x) {
#if __has_builtin(__builtin_amdgcn_exp2f)
    return __builtin_amdgcn_exp2f(x);
#else
    return exp2f(x);
#endif
}

__device__ __forceinline__ u32 cvtpk(float lo, float hi) {
    u32 d;
    asm("v_cvt_pk_bf16_f32 %0, %1, %2" : "=v"(d) : "v"(lo), "v"(hi));
    return d;
}

__device__ __forceinline__ void pl32swap(u32& a, u32& b) {
    asm volatile("v_permlane32_swap_b32 %0, %1" : "+v"(a), "+v"(b));
}

__device__ __forceinline__ void g2l16(const u16* g, u16* l) {
    __builtin_amdgcn_global_load_lds(
        (const __attribute__((address_space(1))) unsigned int*)g,
        (__attribute__((address_space(3))) unsigned int*)l, 16, 0, 0);
}

#define WAITV(N) asm volatile("s_waitcnt vmcnt(" #N ")" ::: "memory")
#define WAITL0   asm volatile("s_waitcnt lgkmcnt(0)" ::: "memory")
#define SBAR     __builtin_amdgcn_s_barrier()
#define SCHED0   __builtin_amdgcn_sched_barrier(0)

// ---------------- prep: convert W, transpose+convert X ----------------
__global__ __launch_bounds__(256) void prep_kernel(
    const float* __restrict__ wq, const float* __restrict__ wk,
    const float* __restrict__ wv, const float* __restrict__ x,
    u16* __restrict__ wcat, u16* __restrict__ xT)
{
    const int bid = blockIdx.x, t = threadIdx.x;
    if (bid < 384) {
        int e0 = bid * 2048 + t * 8;
        const float* src = (e0 < 262144) ? wq : (e0 < 524288) ? wk : wv;
        int eo = e0 & 262143;
        float4 a = *(const float4*)(src + eo);
        float4 b = *(const float4*)(src + eo + 4);
        u16x8 o;
        o[0]=f2b(a.x); o[1]=f2b(a.y); o[2]=f2b(a.z); o[3]=f2b(a.w);
        o[4]=f2b(b.x); o[5]=f2b(b.y); o[6]=f2b(b.z); o[7]=f2b(b.w);
        *(u16x8*)(wcat + e0) = o;
        return;
    }
    int xb = bid - 384;
    int b = xb >> 8, ct = (xb >> 5) & 7, lt = xb & 31;
    __shared__ float lds[64 * 65];
#pragma unroll
    for (int it = 0; it < 4; ++it) {
        int s = t + it * 256;
        int cr = s >> 4, l4 = (s & 15) * 4;
        float4 v = *(const float4*)(x + ((size_t)(b * 512 + ct * 64 + cr)) * 2048 + lt * 64 + l4);
        lds[(l4 + 0) * 65 + cr] = v.x;
        lds[(l4 + 1) * 65 + cr] = v.y;
        lds[(l4 + 2) * 65 + cr] = v.z;
        lds[(l4 + 3) * 65 + cr] = v.w;
    }
    __syncthreads();
    // BUGFIX (round 2 -> 3): exactly ONE 256-item pass here. The old
    // `for it<4` ran l = s>>2 up to 255 -> OOB LDS reads + garbage writes
    // into other tiles' xT rows (and past xT into qt for lt=31).
    {
        int l = t >> 2, c16 = (t & 3) * 16;
        u16x8 o0, o1;
#pragma unroll
        for (int i = 0; i < 8; ++i) o0[i] = f2b(lds[l * 65 + c16 + i]);
#pragma unroll
        for (int i = 0; i < 8; ++i) o1[i] = f2b(lds[l * 65 + c16 + 8 + i]);
        u16* d = xT + ((size_t)(b * 2048 + lt * 64 + l)) * 512 + ct * 64 + c16;
        *(u16x8*)d = o0;
        *(u16x8*)(d + 8) = o1;
    }
}

// ---------------- proj: fused qkv GEMM ----------------
__global__ __launch_bounds__(256) void proj_kernel(
    const u16* __restrict__ wcat, const u16* __restrict__ xT,
    const float* __restrict__ bq, const float* __restrict__ bk,
    const float* __restrict__ bv,
    u16* __restrict__ qt, u16* __restrict__ kt, u16* __restrict__ vv)
{
    const int lt = blockIdx.x, ot = blockIdx.y, b = blockIdx.z;
    const int l0 = lt * 128, o0 = ot * 128;
    const int sel = o0 >> 9, ol0 = o0 & 511;
    const float* __restrict__ bias = (sel == 0) ? bq : (sel == 1) ? bk : bv;

    __shared__ __align__(16) u16 wt[128 * 64];
    __shared__ __align__(16) u16 xt[128 * 64];

    const int tid = threadIdx.x, wid = tid >> 6, lane = tid & 63;
    const int hlf = lane >> 5, i32 = lane & 31;
    const int lrow = lane >> 3, lg = lane & 7;
    const int wo = wid >> 1, wl = wid & 1;

    f32x16 acc[2][2];
#pragma unroll
    for (int a = 0; a < 2; ++a)
#pragma unroll
        for (int c = 0; c < 2; ++c)
#pragma unroll
            for (int r = 0; r < 16; ++r) acc[a][c][r] = 0.f;

    for (int c0 = 0; c0 < 512; c0 += 64) {
#pragma unroll
        for (int cc = 0; cc < 4; ++cc) {
            int rb = (wid * 4 + cc) * 8;
            int rw = rb + lrow;
            int sg = (lg ^ (rw & 7)) << 3;
            g2l16(wcat + (size_t)(o0 + rw) * 512 + c0 + sg, wt + rb * 64);
            g2l16(xT + ((size_t)(b * 2048 + l0 + rw)) * 512 + c0 + sg, xt + rb * 64);
        }
        WAITV(0);
        SBAR;
        SCHED0;
        bf16x8 wf[2][4], xf[2][4];
#pragma unroll
        for (int a = 0; a < 2; ++a)
#pragma unroll
            for (int ks = 0; ks < 4; ++ks) {
                int rw = wo * 64 + a * 32 + i32;
                wf[a][ks] = *(const bf16x8*)(wt + rw * 64 + (((ks * 2 + hlf) ^ (rw & 7)) << 3));
                int rx = wl * 64 + a * 32 + i32;
                xf[a][ks] = *(const bf16x8*)(xt + rx * 64 + (((ks * 2 + hlf) ^ (rx & 7)) << 3));
            }
        if (sel < 2) {
#pragma unroll
            for (int a = 0; a < 2; ++a)
#pragma unroll
                for (int c = 0; c < 2; ++c)
#pragma unroll
                    for (int ks = 0; ks < 4; ++ks)
                        acc[a][c] = __builtin_amdgcn_mfma_f32_32x32x16_bf16(xf[a][ks], wf[c][ks], acc[a][c], 0, 0, 0);
        } else {
#pragma unroll
            for (int a = 0; a < 2; ++a)
#pragma unroll
                for (int c = 0; c < 2; ++c)
#pragma unroll
                    for (int ks = 0; ks < 4; ++ks)
                        acc[a][c] = __builtin_amdgcn_mfma_f32_32x32x16_bf16(wf[a][ks], xf[c][ks], acc[a][c], 0, 0, 0);
        }
        WAITL0;
        SCHED0;
        SBAR;
    }

    if (sel < 2) {
        u16* __restrict__ dst = (sel == 0) ? qt : kt;
        const float sc = (sel == 0) ? SCALE_Q : 1.0f;
#pragma unroll
        for (int c = 0; c < 2; ++c) {
            int cg = ol0 + wo * 64 + c * 32 + i32;
            int h = cg >> 6, c6 = cg & 63;
            float bb = bias[cg];
#pragma unroll
            for (int a = 0; a < 2; ++a)
#pragma unroll
                for (int r = 0; r < 16; ++r) {
                    int l = l0 + wl * 64 + a * 32 + (r & 3) + 8 * (r >> 2) + 4 * hlf;
                    dst[(((size_t)(b * 8 + h)) * 2048 + l) * 64 + c6] = f2b((acc[a][c][r] + bb) * sc);
                }
        }
    } else {
#pragma unroll
        for (int a = 0; a < 2; ++a)
#pragma unroll
            for (int r = 0; r < 16; ++r) {
                int ov = ol0 + wo * 64 + a * 32 + (r & 3) + 8 * (r >> 2) + 4 * hlf;
                float bb = bias[ov];
#pragma unroll
                for (int c = 0; c < 2; ++c) {
                    int l = l0 + wl * 64 + c * 32 + i32;
                    vv[((size_t)(b * 512 + ov)) * 2048 + l] = f2b(acc[a][c][r] + bb);
                }
            }
    }
}

// ---------------- vtrans: V (v2 rows) -> V^T (b,h,c,m) ----------------
__global__ __launch_bounds__(256) void vtrans_kernel(
    const u16* __restrict__ vv, u16* __restrict__ vtg)
{
    const int bh = blockIdx.x >> 5, mt = blockIdx.x & 31;
    const u16* __restrict__ src = vv + (size_t)bh * 131072 + mt * 4096;
    __shared__ u16 lds[64 * 65];
    const int t = threadIdx.x;
    const int m = t >> 2, c16 = (t & 3) * 16;
    u16x8 a = *(const u16x8*)(src + t * 16);
    u16x8 b = *(const u16x8*)(src + t * 16 + 8);
#pragma unroll
    for (int i = 0; i < 8; ++i) lds[(c16 + i) * 65 + m] = a[i];
#pragma unroll
    for (int i = 0; i < 8; ++i) lds[(c16 + 8 + i) * 65 + m] = b[i];
    __syncthreads();
    const int c = t >> 2, m16 = (t & 3) * 16;
    u16x8 o0, o1;
#pragma unroll
    for (int i = 0; i < 8; ++i) o0[i] = lds[c * 65 + m16 + i];
#pragma unroll
    for (int i = 0; i < 8; ++i) o1[i] = lds[c * 65 + m16 + 8 + i];
    u16* d = vtg + (size_t)bh * 131072 + (size_t)c * 2048 + mt * 64 + m16;
    *(u16x8*)d = o0;
    *(u16x8*)(d + 8) = o1;
}

// ---------------- attn: flash, 32x32x16, dbuf ----------------
__global__ __launch_bounds__(128) void attn_kernel(
    const u16* __restrict__ qt, const u16* __restrict__ kt,
    const u16* __restrict__ vtg, float* __restrict__ out)
{
    const int bh = blockIdx.y;
    const int l0 = blockIdx.x * 64;
    const int tid = threadIdx.x, wid = tid >> 6, lane = tid & 63;
    const int hlf = lane >> 5, i32 = lane & 31;
    const int lrow = lane >> 3, lg = lane & 7;

    __shared__ __align__(16) u16 smem[16384];
    float* olds = (float*)smem;

    bf16x8 qf[4];
    {
        const u16* qrow = qt + ((size_t)bh * 2048 + l0 + wid * 32 + i32) * 64;
#pragma unroll
        for (int ks = 0; ks < 4; ++ks)
            qf[ks] = *(const bf16x8*)(qrow + ks * 16 + hlf * 8);
    }
    const u16* __restrict__ kb = kt + (size_t)bh * 2048 * 64;
    const u16* __restrict__ vb = vtg + (size_t)bh * 131072;

    float m_run = -1e30f, l_run = 0.f;
    f32x16 oacc[2];
#pragma unroll
    for (int c = 0; c < 2; ++c)
#pragma unroll
        for (int r = 0; r < 16; ++r) oacc[c][r] = 0.f;

#define STAGE(T, BUF) do {                                                        \
    if (wid == 0) {                                                               \
        _Pragma("unroll")                                                         \
        for (int cc = 0; cc < 8; ++cc) {                                          \
            int mrow = (T) * 64 + cc * 8 + lrow;                                  \
            g2l16(kb + (size_t)mrow * 64 + ((lg ^ lrow) << 3),                    \
                  smem + (BUF) * 4096 + cc * 512);                                \
        }                                                                         \
    } else {                                                                      \
        _Pragma("unroll")                                                         \
        for (int cc = 0; cc < 8; ++cc) {                                          \
            int crow = cc * 8 + lrow;                                             \
            g2l16(vb + (size_t)crow * 2048 + (T) * 64 + ((lg ^ lrow) << 3),       \
                  smem + 8192 + (BUF) * 4096 + cc * 512);                         \
        }                                                                         \
    } } while (0)

    STAGE(0, 0);

    for (int t = 0; t < 32; ++t) {
        const int cb = t & 1;
        if (t < 31) {
            STAGE(t + 1, cb ^ 1);
            WAITV(8);
        } else {
            WAITV(0);
        }
        SBAR;
        SCHED0;

        const u16* kbuf = smem + cb * 4096;
        const u16* vbuf = smem + 8192 + cb * 4096;

        // St = K . Q^T  (D[m][l])
        f32x16 st[2];
#pragma unroll
        for (int mi = 0; mi < 2; ++mi) {
#pragma unroll
            for (int r = 0; r < 16; ++r) st[mi][r] = 0.f;
#pragma unroll
            for (int ks = 0; ks < 4; ++ks) {
                int row = mi * 32 + i32;
                bf16x8 kf = *(const bf16x8*)(kbuf + row * 64 + (((ks * 2 + hlf) ^ (row & 7)) << 3));
                st[mi] = __builtin_amdgcn_mfma_f32_32x32x16_bf16(kf, qf[ks], st[mi], 0, 0, 0);
            }
        }

        // online softmax (per l = lane&31; partner = lane^32)
        float pmax = st[0][0];
#pragma unroll
        for (int mi = 0; mi < 2; ++mi)
#pragma unroll
            for (int r = 0; r < 16; ++r) pmax = fmaxf(pmax, st[mi][r]);
        pmax = fmaxf(pmax, __shfl_xor(pmax, 32));
        float m_new = fmaxf(m_run, pmax);
        float corr = exp2_(m_run - m_new);
        float psum = 0.f;
#pragma unroll
        for (int mi = 0; mi < 2; ++mi)
#pragma unroll
            for (int r = 0; r < 16; ++r) {
                st[mi][r] = exp2_(st[mi][r] - m_new);
                psum += st[mi][r];
            }
        psum += __shfl_xor(psum, 32);
        l_run = l_run * corr + psum;
        m_run = m_new;
#pragma unroll
        for (int c = 0; c < 2; ++c)
#pragma unroll
            for (int r = 0; r < 16; ++r) oacc[c][r] *= corr;

        // P -> B-fragments in-register (cvt_pk + permlane32_swap)
        bf16x8 pf[4];
#pragma unroll
        for (int ks = 0; ks < 4; ++ks) {
            int mi = ks >> 1, rb = (ks & 1) * 8;
            u32 A1 = cvtpk(st[mi][rb + 0], st[mi][rb + 1]);
            u32 B1 = cvtpk(st[mi][rb + 2], st[mi][rb + 3]);
            u32 A2 = cvtpk(st[mi][rb + 4], st[mi][rb + 5]);
            u32 B2 = cvtpk(st[mi][rb + 6], st[mi][rb + 7]);
            pl32swap(A1, A2);
            pl32swap(B1, B2);
            union { u32 w[4]; bf16x8 v; } u;
            u.w[0] = A1; u.w[1] = B1; u.w[2] = A2; u.w[3] = B2;
            pf[ks] = u.v;
        }

        // O^T += V^T . P^T
#pragma unroll
        for (int ci = 0; ci < 2; ++ci)
#pragma unroll
            for (int ks = 0; ks < 4; ++ks) {
                int row = ci * 32 + i32;
                bf16x8 vf = *(const bf16x8*)(vbuf + row * 64 + (((ks * 2 + hlf) ^ (row & 7)) << 3));
                oacc[ci] = __builtin_amdgcn_mfma_f32_32x32x16_bf16(vf, pf[ks], oacc[ci], 0, 0, 0);
            }

        WAITL0;
        SCHED0;
        SBAR;
    }

    // epilogue: transpose O via LDS (overlays staging bufs; loop's final SBAR done)
    float inv = 1.0f / l_run;
    int ll = wid * 32 + i32;
#pragma unroll
    for (int ci = 0; ci < 2; ++ci)
#pragma unroll
        for (int r = 0; r < 16; ++r) {
            int c = ci * 32 + (r & 3) + 8 * (r >> 2) + 4 * hlf;
            olds[ll * 64 + (c ^ ((ll & 7) << 2))] = oacc[ci][r] * inv;
        }
    __syncthreads();
    {
        int l = tid >> 1, hv = tid & 1;
        float* orow = out + ((size_t)bh * 2048 + l0 + l) * 64;
#pragma unroll
        for (int i = 0; i < 8; ++i) {
            int c4 = hv * 8 + i;
            float4 v = *(const float4*)(olds + l * 64 + ((c4 ^ (l & 7)) << 2));
            *(float4*)(orow + c4 * 4) = v;
        }
    }
#undef STAGE
}

extern "C" void kernel_launch(void* const* d_in, const int* in_sizes, int n_in,
                              void* d_out, int out_size, void* d_ws, size_t ws_size,
                              hipStream_t stream) {
    const float* x  = (const float*)d_in[0];
    const float* wq = (const float*)d_in[1];
    const float* bq = (const float*)d_in[2];
    const float* wk = (const float*)d_in[3];
    const float* bk = (const float*)d_in[4];
    const float* wv = (const float*)d_in[5];
    const float* bv = (const float*)d_in[6];
    float* out = (float*)d_out;

    u16* wcat = (u16*)d_ws;                 // 786432
    u16* xT   = wcat + 786432;              // 4194304
    u16* qt   = xT + 4194304;
    u16* kt   = qt + 4194304;
    u16* vv   = kt + 4194304;
    u16* vtg  = vv + 4194304;

    prep_kernel<<<1408, 256, 0, stream>>>(wq, wk, wv, x, wcat, xT);
    proj_kernel<<<dim3(16, 12, 4), 256, 0, stream>>>(wcat, xT, bq, bk, bv, qt, kt, vv);
    vtrans_kernel<<<1024, 256, 0, stream>>>(vv, vtg);
    attn_kernel<<<dim3(32, 32), 128, 0, stream>>>(qt, kt, vtg, out);
}